// Round 1
// baseline (504.879 us; speedup 1.0000x reference)
//
#include <hip/hip_runtime.h>

typedef unsigned short u16;
typedef short s16x8 __attribute__((ext_vector_type(8)));
typedef u16 u16x4 __attribute__((ext_vector_type(4)));
typedef float f32x4 __attribute__((ext_vector_type(4)));

#define B_ 32
#define L_ 256
#define D_ 1024
#define H_ 8
#define DQ_ 128
#define DS_ 64
#define DM_ 256
#define DF_ 4096

__device__ __forceinline__ u16 f2bf(float f) {
  unsigned u = __float_as_uint(f);
  unsigned r = (u + 0x7FFFu + ((u >> 16) & 1u)) >> 16;
  return (u16)r;
}

__device__ __forceinline__ f32x4 mfma16(s16x8 a, s16x8 b, f32x4 c) {
  return __builtin_amdgcn_mfma_f32_16x16x32_bf16(a, b, c, 0, 0, 0);
}

#define GLDS16(g, l)                                                        \
  __builtin_amdgcn_global_load_lds(                                         \
      (__attribute__((address_space(1))) const void*)(g),                   \
      (__attribute__((address_space(3))) void*)(l), 16, 0, 0)

// ---------------- transpose + f32->bf16 convert: in [K][N] f32 -> out [N][K] bf16
__global__ __launch_bounds__(256) void tconv(const float* __restrict__ in,
                                             u16* __restrict__ out, int K, int N,
                                             long sIn, long sOut) {
  __shared__ float t[32][33];
  const int tx = threadIdx.x & 31, ty = threadIdx.x >> 5;  // ty 0..7
  const long n0 = (long)blockIdx.x * 32, k0 = (long)blockIdx.y * 32;
  const float* ip = in + (long)blockIdx.z * sIn;
  u16* op = out + (long)blockIdx.z * sOut;
#pragma unroll
  for (int i = 0; i < 4; ++i)
    t[ty + i * 8][tx] = ip[(k0 + ty + i * 8) * N + n0 + tx];
  __syncthreads();
#pragma unroll
  for (int i = 0; i < 4; ++i)
    op[(n0 + ty + i * 8) * K + k0 + tx] = f2bf(t[tx][ty + i * 8]);
}

// ---------------- elementwise f32->bf16 (src batch 0)
__global__ __launch_bounds__(256) void conv_bf16(const float* __restrict__ in,
                                                 u16* __restrict__ out) {
  const int i = (blockIdx.x * 256 + threadIdx.x) * 4;
  float4 v = *(const float4*)(in + i);
  u16x4 o = {f2bf(v.x), f2bf(v.y), f2bf(v.z), f2bf(v.w)};
  *(u16x4*)(out + i) = o;
}

// ---------------- hid = relu(sf[0] @ b1w + b1b), compacted nonzero list per head
__global__ __launch_bounds__(256) void hid_kernel(
    const float* __restrict__ sf, const float* __restrict__ b1w,
    const float* __restrict__ b1b, float* __restrict__ nzv,
    int* __restrict__ nzi, int* __restrict__ nzcnt) {
  const int h = blockIdx.x;
  const int tid = threadIdx.x;
  __shared__ float s_sf[DS_];
  __shared__ int wcnt[4];
  if (tid < DS_) s_sf[tid] = sf[tid];
  __syncthreads();
  float a = b1b[h * DM_ + tid];
  const float* wp = b1w + (long)h * DS_ * DM_ + tid;
#pragma unroll 8
  for (int s = 0; s < DS_; ++s) a += s_sf[s] * wp[s * DM_];
  a = fmaxf(a, 0.f);
  const unsigned long long bal = __ballot(a > 0.f);
  const int lane = tid & 63, wv = tid >> 6;
  const int pc = __popcll(bal);
  if (lane == 0) wcnt[wv] = pc;
  __syncthreads();
  int base = 0;
  for (int i = 0; i < wv; ++i) base += wcnt[i];
  const int pos = base + __popcll(bal & ((1ull << lane) - 1ull));
  if (a > 0.f) { nzv[h * DM_ + pos] = a; nzi[h * DM_ + pos] = tid; }
  if (tid == 255) nzcnt[h] = base + pc;
}

// ---------------- bias[h][n] = sum_m hid[h][m]*b2w[h][m][n] + b2b[h][n] (skip zero rows)
__global__ __launch_bounds__(256) void bias_gemv(
    const float* __restrict__ nzv, const int* __restrict__ nzi,
    const int* __restrict__ nzcnt, const float* __restrict__ b2w,
    const float* __restrict__ b2b, float* __restrict__ biasb) {
  const int h = blockIdx.y;
  const int n0 = blockIdx.x * 1024;
  const int tid = threadIdx.x;
  __shared__ float sv[DM_];
  __shared__ int si[DM_];
  const int nnz = nzcnt[h];
  if (tid < DM_) { sv[tid] = nzv[h * DM_ + tid]; si[tid] = nzi[h * DM_ + tid]; }
  __syncthreads();
  const float* wb = b2w + (long)h * DM_ * 65536 + n0 + tid * 4;
  float4 acc = {0.f, 0.f, 0.f, 0.f};
  int j = 0;
  for (; j + 4 <= nnz; j += 4) {
    const float4 a0 = *(const float4*)(wb + (long)si[j] * 65536);
    const float4 a1 = *(const float4*)(wb + (long)si[j + 1] * 65536);
    const float4 a2 = *(const float4*)(wb + (long)si[j + 2] * 65536);
    const float4 a3 = *(const float4*)(wb + (long)si[j + 3] * 65536);
    const float v0 = sv[j], v1 = sv[j + 1], v2 = sv[j + 2], v3 = sv[j + 3];
    acc.x += v0 * a0.x + v1 * a1.x + v2 * a2.x + v3 * a3.x;
    acc.y += v0 * a0.y + v1 * a1.y + v2 * a2.y + v3 * a3.y;
    acc.z += v0 * a0.z + v1 * a1.z + v2 * a2.z + v3 * a3.z;
    acc.w += v0 * a0.w + v1 * a1.w + v2 * a2.w + v3 * a3.w;
  }
  for (; j < nnz; ++j) {
    const float4 a0 = *(const float4*)(wb + (long)si[j] * 65536);
    const float v0 = sv[j];
    acc.x += v0 * a0.x; acc.y += v0 * a0.y; acc.z += v0 * a0.z; acc.w += v0 * a0.w;
  }
  const float4 bb = *(const float4*)(b2b + (long)h * 65536 + n0 + tid * 4);
  float4 o = {acc.x + bb.x, acc.y + bb.y, acc.z + bb.z, acc.w + bb.w};
  *(float4*)(biasb + (long)h * 65536 + n0 + tid * 4) = o;
}

// ---------------- generic 128x128x(K) bf16 MFMA GEMM, A [M][K], BT [N][K]
// EPI: 0 = f32 out +bias; 1 = bf16 out relu(+bias); 2 = bf16 out +bias;
//      3 = bf16 out transposed +bias; 4 = f32 out +bias +residual R (in-place ok)
template <int EPI>
__global__ __launch_bounds__(256) void gemm_bt(
    const u16* __restrict__ A, const u16* __restrict__ BT, void* __restrict__ Cv,
    const float* __restrict__ bias, const float* __restrict__ R, int K, long sA,
    long sBT, long sC, long sBias, int ldc) {
  __shared__ u16 smA[128 * 32];
  __shared__ u16 smB[128 * 32];
  const int tid = threadIdx.x;
  const int lane = tid & 63;
  const int wv = tid >> 6;
  const int wr = wv >> 1, wc = wv & 1;
  const long tm = (long)blockIdx.x * 128;
  const long tn = (long)blockIdx.y * 128;
  const int z = blockIdx.z;
  A += (long)z * sA;
  BT += (long)z * sBT;

  const u16* ga = A + (tm + (tid >> 2)) * (long)K + (tid & 3) * 8;
  const u16* gb = BT + (tn + (tid >> 2)) * (long)K + (tid & 3) * 8;
  const long rstep = 64L * K;
  u16* la = &smA[tid * 8];
  u16* lb = &smB[tid * 8];

  f32x4 acc[4][4];
#pragma unroll
  for (int m = 0; m < 4; ++m)
#pragma unroll
    for (int n = 0; n < 4; ++n) acc[m][n] = (f32x4){0.f, 0.f, 0.f, 0.f};

  for (int k0 = 0; k0 < K; k0 += 32) {
    GLDS16(ga + k0, la);
    GLDS16(ga + rstep + k0, la + 64 * 32);
    GLDS16(gb + k0, lb);
    GLDS16(gb + rstep + k0, lb + 64 * 32);
    __syncthreads();
    s16x8 af[4], bf[4];
    const int ka = (lane >> 4) * 8;
    const int ra = wr * 64 + (lane & 15);
    const int rb = wc * 64 + (lane & 15);
#pragma unroll
    for (int m = 0; m < 4; ++m) af[m] = *(const s16x8*)&smA[(ra + m * 16) * 32 + ka];
#pragma unroll
    for (int n = 0; n < 4; ++n) bf[n] = *(const s16x8*)&smB[(rb + n * 16) * 32 + ka];
#pragma unroll
    for (int m = 0; m < 4; ++m)
#pragma unroll
      for (int n = 0; n < 4; ++n) acc[m][n] = mfma16(af[m], bf[n], acc[m][n]);
    __syncthreads();
  }

  const long crow0 = tm + wr * 64 + ((lane >> 4) * 4);
  const long ccol0 = tn + wc * 64 + (lane & 15);
#pragma unroll
  for (int m = 0; m < 4; ++m) {
#pragma unroll
    for (int n = 0; n < 4; ++n) {
#pragma unroll
      for (int i = 0; i < 4; ++i) {
        const long row = crow0 + m * 16 + i;
        const long col = ccol0 + n * 16;
        float v = acc[m][n][i] + bias[(long)z * sBias + col];
        if constexpr (EPI == 0) {
          ((float*)Cv)[(long)z * sC + row * ldc + col] = v;
        } else if constexpr (EPI == 1) {
          ((u16*)Cv)[(long)z * sC + row * ldc + col] = f2bf(fmaxf(v, 0.f));
        } else if constexpr (EPI == 2) {
          ((u16*)Cv)[(long)z * sC + row * ldc + col] = f2bf(v);
        } else if constexpr (EPI == 3) {
          ((u16*)Cv)[(long)z * sC + col * ldc + row] = f2bf(v);
        } else {
          ((float*)Cv)[row * (long)ldc + col] = v + R[row * (long)ldc + col];
        }
      }
    }
  }
}

// ---------------- fused attention for batch 0, one wave per (head, 16-row tile)
__global__ __launch_bounds__(64) void attn_kernel(
    const u16* __restrict__ q0, const u16* __restrict__ k0,
    const u16* __restrict__ vT, const float* __restrict__ biasb,
    const int* __restrict__ mask0, u16* __restrict__ hidden) {
  const int lane = threadIdx.x;
  const int h = blockIdx.y;
  const int r0 = blockIdx.x * 16;
  const u16* q = q0 + (long)h * L_ * DQ_;
  const u16* k = k0 + (long)h * L_ * DQ_;
  const u16* v = vT + (long)h * DQ_ * L_;
  const int lg = lane >> 4;  // 0..3
  const int ll = lane & 15;

  s16x8 aq[4];
#pragma unroll
  for (int kk = 0; kk < 4; ++kk)
    aq[kk] = *(const s16x8*)(q + (long)(r0 + ll) * DQ_ + kk * 32 + lg * 8);

  float sc[16][4];
  const float scale = 0.08838834764831845f;  // 1/sqrt(128)
#pragma unroll
  for (int t = 0; t < 16; ++t) {
    f32x4 a = {0.f, 0.f, 0.f, 0.f};
#pragma unroll
    for (int kk = 0; kk < 4; ++kk) {
      s16x8 bf = *(const s16x8*)(k + (long)(t * 16 + ll) * DQ_ + kk * 32 + lg * 8);
      a = mfma16(aq[kk], bf, a);
    }
#pragma unroll
    for (int i = 0; i < 4; ++i) {
      const int row = r0 + lg * 4 + i;
      const int col = t * 16 + ll;
      float s = a[i] * scale;
      if (mask0[row * L_ + col] != 0) s = 1e-9f;
      sc[t][i] = s;
    }
  }
  // row-wise softmax (each row lives on 16 lanes sharing lg), then +bias
#pragma unroll
  for (int i = 0; i < 4; ++i) {
    float mx = sc[0][i];
#pragma unroll
    for (int t = 1; t < 16; ++t) mx = fmaxf(mx, sc[t][i]);
#pragma unroll
    for (int d = 1; d < 16; d <<= 1) mx = fmaxf(mx, __shfl_xor(mx, d));
    float sum = 0.f;
#pragma unroll
    for (int t = 0; t < 16; ++t) {
      const float e = __expf(sc[t][i] - mx);
      sc[t][i] = e;
      sum += e;
    }
#pragma unroll
    for (int d = 1; d < 16; d <<= 1) sum += __shfl_xor(sum, d);
    const float inv = 1.f / sum;
    const int row = r0 + lg * 4 + i;
#pragma unroll
    for (int t = 0; t < 16; ++t)
      sc[t][i] = sc[t][i] * inv + biasb[(long)h * 65536 + (long)row * 256 + t * 16 + ll];
  }
  // transpose soft tile via LDS for PV A-operand
  __shared__ float sm[16 * 256];
#pragma unroll
  for (int t = 0; t < 16; ++t)
#pragma unroll
    for (int i = 0; i < 4; ++i)
      sm[(lg * 4 + i) * 256 + t * 16 + ll] = sc[t][i];
  __syncthreads();
  s16x8 af[8];
#pragma unroll
  for (int kk = 0; kk < 8; ++kk) {
    const float* ap = &sm[ll * 256 + kk * 32 + lg * 8];
    s16x8 t8;
#pragma unroll
    for (int j = 0; j < 8; ++j) t8[j] = (short)f2bf(ap[j]);
    af[kk] = t8;
  }
#pragma unroll
  for (int n = 0; n < 8; ++n) {
    f32x4 a = {0.f, 0.f, 0.f, 0.f};
#pragma unroll
    for (int kk = 0; kk < 8; ++kk) {
      s16x8 bf = *(const s16x8*)(v + (long)(n * 16 + ll) * 256 + kk * 32 + lg * 8);
      a = mfma16(af[kk], bf, a);
    }
#pragma unroll
    for (int i = 0; i < 4; ++i) {
      const int row = r0 + lg * 4 + i;
      const int col = n * 16 + ll;
      hidden[(long)row * 1024 + h * 128 + col] = f2bf(a[i]);
    }
  }
}

// ---------------- layernorm over D=1024; optional add of attn row (row%L); dual out
__global__ __launch_bounds__(256) void ln_kernel(
    const float* __restrict__ in0, const float* __restrict__ add1,
    const float* __restrict__ g, const float* __restrict__ bb,
    float* __restrict__ outf, u16* __restrict__ outb) {
  const int tid = threadIdx.x;
  const long row = blockIdx.x;
  float4 v = ((const float4*)(in0 + row * D_))[tid];
  if (add1) {
    const float4 u = ((const float4*)(add1 + (row & (L_ - 1)) * D_))[tid];
    v.x += u.x; v.y += u.y; v.z += u.z; v.w += u.w;
  }
  float s = v.x + v.y + v.z + v.w;
  float q = v.x * v.x + v.y * v.y + v.z * v.z + v.w * v.w;
#pragma unroll
  for (int d = 1; d < 64; d <<= 1) { s += __shfl_xor(s, d); q += __shfl_xor(q, d); }
  __shared__ float ss[4], sq[4];
  const int wv = tid >> 6;
  if ((tid & 63) == 0) { ss[wv] = s; sq[wv] = q; }
  __syncthreads();
  s = ss[0] + ss[1] + ss[2] + ss[3];
  q = sq[0] + sq[1] + sq[2] + sq[3];
  const float mu = s * (1.f / D_);
  const float var = q * (1.f / D_) - mu * mu;
  const float rs = rsqrtf(var + 1e-5f);
  const float4 gv = ((const float4*)g)[tid];
  const float4 bv = ((const float4*)bb)[tid];
  float4 o;
  o.x = (v.x - mu) * rs * gv.x + bv.x;
  o.y = (v.y - mu) * rs * gv.y + bv.y;
  o.z = (v.z - mu) * rs * gv.z + bv.z;
  o.w = (v.w - mu) * rs * gv.w + bv.w;
  ((float4*)(outf + row * D_))[tid] = o;
  if (outb) {
    uint2 pk;
    pk.x = (unsigned)f2bf(o.x) | ((unsigned)f2bf(o.y) << 16);
    pk.y = (unsigned)f2bf(o.z) | ((unsigned)f2bf(o.w) << 16);
    *(uint2*)(outb + row * D_ + tid * 4) = pk;
  }
}

extern "C" void kernel_launch(void* const* d_in, const int* in_sizes, int n_in,
                              void* d_out, int out_size, void* d_ws, size_t ws_size,
                              hipStream_t stream) {
  (void)in_sizes; (void)n_in; (void)out_size; (void)ws_size;
  const float* src = (const float*)d_in[0];
  const float* sf = (const float*)d_in[1];
  const int* mask = (const int*)d_in[2];
  const float* qw = (const float*)d_in[3];
  const float* qb = (const float*)d_in[4];
  const float* kw = (const float*)d_in[5];
  const float* kb = (const float*)d_in[6];
  const float* vw = (const float*)d_in[7];
  const float* vb = (const float*)d_in[8];
  const float* b1w = (const float*)d_in[9];
  const float* b1b = (const float*)d_in[10];
  const float* b2w = (const float*)d_in[11];
  const float* b2b = (const float*)d_in[12];
  const float* ow = (const float*)d_in[13];
  const float* ob = (const float*)d_in[14];
  const float* ln1g = (const float*)d_in[15];
  const float* ln1b = (const float*)d_in[16];
  const float* ln2g = (const float*)d_in[17];
  const float* ln2b = (const float*)d_in[18];
  const float* w1 = (const float*)d_in[19];
  const float* bf1 = (const float*)d_in[20];
  const float* w2 = (const float*)d_in[21];
  const float* bf2 = (const float*)d_in[22];
  float* out = (float*)d_out;

  char* ws = (char*)d_ws;
  size_t off = 0;
  auto alloc = [&](size_t bytes) {
    void* p = ws + off;
    off += (bytes + 255) & ~(size_t)255;
    return p;
  };
  u16* qwT = (u16*)alloc((size_t)H_ * DQ_ * D_ * 2);
  u16* kwT = (u16*)alloc((size_t)H_ * DQ_ * D_ * 2);
  u16* vwT = (u16*)alloc((size_t)H_ * DQ_ * D_ * 2);
  u16* owT = (u16*)alloc((size_t)D_ * D_ * 2);
  u16* w1T = (u16*)alloc((size_t)DF_ * D_ * 2);
  u16* w2T = (u16*)alloc((size_t)D_ * DF_ * 2);
  u16* src0b = (u16*)alloc((size_t)L_ * D_ * 2);
  u16* q0 = (u16*)alloc((size_t)H_ * L_ * DQ_ * 2);
  u16* k0 = (u16*)alloc((size_t)H_ * L_ * DQ_ * 2);
  u16* v0T = (u16*)alloc((size_t)H_ * DQ_ * L_ * 2);
  float* nzv = (float*)alloc((size_t)H_ * DM_ * 4);
  int* nzi = (int*)alloc((size_t)H_ * DM_ * 4);
  int* nzcnt = (int*)alloc(256);
  float* biasb = (float*)alloc((size_t)H_ * L_ * L_ * 4);
  u16* hidden = (u16*)alloc((size_t)L_ * H_ * DQ_ * 2);
  float* attnvec = (float*)alloc((size_t)L_ * D_ * 4);
  float* xf = (float*)alloc((size_t)B_ * L_ * D_ * 4);
  u16* xb = (u16*)alloc((size_t)B_ * L_ * D_ * 2);
  u16* ffnh = (u16*)alloc((size_t)B_ * L_ * DF_ * 2);
  // total ~149 MB

  const dim3 b256(256);
  // weight transpose+convert
  tconv<<<dim3(DQ_ / 32, D_ / 32, H_), b256, 0, stream>>>(
      qw, qwT, D_, DQ_, (long)D_ * DQ_, (long)DQ_ * D_);
  tconv<<<dim3(DQ_ / 32, D_ / 32, H_), b256, 0, stream>>>(
      kw, kwT, D_, DQ_, (long)D_ * DQ_, (long)DQ_ * D_);
  tconv<<<dim3(DQ_ / 32, D_ / 32, H_), b256, 0, stream>>>(
      vw, vwT, D_, DQ_, (long)D_ * DQ_, (long)DQ_ * D_);
  tconv<<<dim3(D_ / 32, D_ / 32, 1), b256, 0, stream>>>(ow, owT, D_, D_, 0, 0);
  tconv<<<dim3(DF_ / 32, D_ / 32, 1), b256, 0, stream>>>(w1, w1T, D_, DF_, 0, 0);
  tconv<<<dim3(D_ / 32, DF_ / 32, 1), b256, 0, stream>>>(w2, w2T, DF_, D_, 0, 0);
  conv_bf16<<<dim3(L_ * D_ / 1024), b256, 0, stream>>>(src, src0b);

  // bias MLP (only sf[0] needed) + big GEMV over b2w with zero-row skipping
  hid_kernel<<<dim3(H_), b256, 0, stream>>>(sf, b1w, b1b, nzv, nzi, nzcnt);
  bias_gemv<<<dim3(64, H_), b256, 0, stream>>>(nzv, nzi, nzcnt, b2w, b2b, biasb);

  // QKV projections for batch 0 only
  gemm_bt<2><<<dim3(2, 1, H_), b256, 0, stream>>>(
      src0b, qwT, q0, qb, nullptr, D_, 0, (long)DQ_ * D_, (long)L_ * DQ_, DQ_, DQ_);
  gemm_bt<2><<<dim3(2, 1, H_), b256, 0, stream>>>(
      src0b, kwT, k0, kb, nullptr, D_, 0, (long)DQ_ * D_, (long)L_ * DQ_, DQ_, DQ_);
  gemm_bt<3><<<dim3(2, 1, H_), b256, 0, stream>>>(
      src0b, vwT, v0T, vb, nullptr, D_, 0, (long)DQ_ * D_, (long)DQ_ * L_, DQ_, L_);

  // attention (b=0), writes hidden [L][H*DQ] bf16
  attn_kernel<<<dim3(16, H_), dim3(64), 0, stream>>>(q0, k0, v0T, biasb, mask, hidden);

  // attn out projection -> attnvec [L][D] f32
  gemm_bt<0><<<dim3(2, 8, 1), b256, 0, stream>>>(
      hidden, owT, attnvec, ob, nullptr, D_, 0, 0, 0, 0, D_);

  // LN1: x = LN(src + attn[None]) -> xf (f32) + xb (bf16)
  ln_kernel<<<dim3(B_ * L_), b256, 0, stream>>>(src, attnvec, ln1g, ln1b, xf, xb);

  // FFN1: relu(x @ w1 + bf1) -> ffnh bf16
  gemm_bt<1><<<dim3(64, 32, 1), b256, 0, stream>>>(
      xb, w1T, ffnh, bf1, nullptr, D_, 0, 0, 0, 0, DF_);
  // FFN2: xf = ffnh @ w2 + bf2 + xf (residual fused, in-place)
  gemm_bt<4><<<dim3(64, 8, 1), b256, 0, stream>>>(
      ffnh, w2T, xf, bf2, xf, DF_, 0, 0, 0, 0, D_);

  // LN2 -> d_out
  ln_kernel<<<dim3(B_ * L_), b256, 0, stream>>>(xf, nullptr, ln2g, ln2b, out, nullptr);
}

// Round 2
// 364.200 us; speedup vs baseline: 1.3863x; 1.3863x over previous
//
#include <hip/hip_runtime.h>

typedef unsigned short u16;
typedef short s16x8 __attribute__((ext_vector_type(8)));
typedef u16 u16x4 __attribute__((ext_vector_type(4)));
typedef float f32x4 __attribute__((ext_vector_type(4)));

#define B_ 32
#define L_ 256
#define D_ 1024
#define H_ 8
#define DQ_ 128
#define DS_ 64
#define DM_ 256
#define DF_ 4096

__device__ __forceinline__ u16 f2bf(float f) {
  unsigned u = __float_as_uint(f);
  unsigned r = (u + 0x7FFFu + ((u >> 16) & 1u)) >> 16;
  return (u16)r;
}

__device__ __forceinline__ f32x4 mfma16(s16x8 a, s16x8 b, f32x4 c) {
  return __builtin_amdgcn_mfma_f32_16x16x32_bf16(a, b, c, 0, 0, 0);
}

#define GLDS16(g, l)                                                        \
  __builtin_amdgcn_global_load_lds(                                         \
      (__attribute__((address_space(1))) const void*)(g),                   \
      (__attribute__((address_space(3))) void*)(l), 16, 0, 0)

// ---------------- transpose + f32->bf16 convert: in [K][N] f32 -> out [N][K] bf16
__global__ __launch_bounds__(256) void tconv(const float* __restrict__ in,
                                             u16* __restrict__ out, int K, int N,
                                             long sIn, long sOut) {
  __shared__ float t[32][33];
  const int tx = threadIdx.x & 31, ty = threadIdx.x >> 5;
  const long n0 = (long)blockIdx.x * 32, k0 = (long)blockIdx.y * 32;
  const float* ip = in + (long)blockIdx.z * sIn;
  u16* op = out + (long)blockIdx.z * sOut;
#pragma unroll
  for (int i = 0; i < 4; ++i)
    t[ty + i * 8][tx] = ip[(k0 + ty + i * 8) * N + n0 + tx];
  __syncthreads();
#pragma unroll
  for (int i = 0; i < 4; ++i)
    op[(n0 + ty + i * 8) * K + k0 + tx] = f2bf(t[tx][ty + i * 8]);
}

// merged q/k/v weight transpose: z = sel*8 + h
__global__ __launch_bounds__(256) void tconv_qkv(const float* __restrict__ qw,
                                                 const float* __restrict__ kw,
                                                 const float* __restrict__ vw,
                                                 u16* __restrict__ qwT,
                                                 u16* __restrict__ kwT,
                                                 u16* __restrict__ vwT) {
  __shared__ float t[32][33];
  const int tx = threadIdx.x & 31, ty = threadIdx.x >> 5;
  const long n0 = (long)blockIdx.x * 32, k0 = (long)blockIdx.y * 32;
  const int z = blockIdx.z, sel = z >> 3, h = z & 7;
  const float* ip = (sel == 0 ? qw : (sel == 1 ? kw : vw)) + (long)h * D_ * DQ_;
  u16* op = (sel == 0 ? qwT : (sel == 1 ? kwT : vwT)) + (long)h * DQ_ * D_;
#pragma unroll
  for (int i = 0; i < 4; ++i)
    t[ty + i * 8][tx] = ip[(k0 + ty + i * 8) * DQ_ + n0 + tx];
  __syncthreads();
#pragma unroll
  for (int i = 0; i < 4; ++i)
    op[(n0 + ty + i * 8) * D_ + k0 + tx] = f2bf(t[tx][ty + i * 8]);
}

// ---------------- elementwise f32->bf16 (src batch 0)
__global__ __launch_bounds__(256) void conv_bf16(const float* __restrict__ in,
                                                 u16* __restrict__ out) {
  const int i = (blockIdx.x * 256 + threadIdx.x) * 4;
  float4 v = *(const float4*)(in + i);
  u16x4 o = {f2bf(v.x), f2bf(v.y), f2bf(v.z), f2bf(v.w)};
  *(u16x4*)(out + i) = o;
}

// ---------------- hid = relu(sf[0] @ b1w + b1b), compacted nonzero list per head
__global__ __launch_bounds__(256) void hid_kernel(
    const float* __restrict__ sf, const float* __restrict__ b1w,
    const float* __restrict__ b1b, float* __restrict__ nzv,
    int* __restrict__ nzi, int* __restrict__ nzcnt) {
  const int h = blockIdx.x;
  const int tid = threadIdx.x;
  __shared__ float s_sf[DS_];
  __shared__ int wcnt[4];
  if (tid < DS_) s_sf[tid] = sf[tid];
  __syncthreads();
  float a = b1b[h * DM_ + tid];
  const float* wp = b1w + (long)h * DS_ * DM_ + tid;
#pragma unroll 8
  for (int s = 0; s < DS_; ++s) a += s_sf[s] * wp[s * DM_];
  a = fmaxf(a, 0.f);
  const unsigned long long bal = __ballot(a > 0.f);
  const int lane = tid & 63, wv = tid >> 6;
  const int pc = __popcll(bal);
  if (lane == 0) wcnt[wv] = pc;
  __syncthreads();
  int base = 0;
  for (int i = 0; i < wv; ++i) base += wcnt[i];
  const int pos = base + __popcll(bal & ((1ull << lane) - 1ull));
  if (a > 0.f) { nzv[h * DM_ + pos] = a; nzi[h * DM_ + pos] = tid; }
  if (tid == 255) nzcnt[h] = base + pc;
}

// ---------------- bias[h][n] = sum_m hid[h][m]*b2w[h][m][n] + b2b[h][n]
__global__ __launch_bounds__(256) void bias_gemv(
    const float* __restrict__ nzv, const int* __restrict__ nzi,
    const int* __restrict__ nzcnt, const float* __restrict__ b2w,
    const float* __restrict__ b2b, float* __restrict__ biasb) {
  const int h = blockIdx.y;
  const int n0 = blockIdx.x * 1024;
  const int tid = threadIdx.x;
  __shared__ float sv[DM_];
  __shared__ int si[DM_];
  const int nnz = nzcnt[h];
  if (tid < DM_) { sv[tid] = nzv[h * DM_ + tid]; si[tid] = nzi[h * DM_ + tid]; }
  __syncthreads();
  const float* wb = b2w + (long)h * DM_ * 65536 + n0 + tid * 4;
  float4 acc = {0.f, 0.f, 0.f, 0.f};
  int j = 0;
  for (; j + 4 <= nnz; j += 4) {
    const float4 a0 = *(const float4*)(wb + (long)si[j] * 65536);
    const float4 a1 = *(const float4*)(wb + (long)si[j + 1] * 65536);
    const float4 a2 = *(const float4*)(wb + (long)si[j + 2] * 65536);
    const float4 a3 = *(const float4*)(wb + (long)si[j + 3] * 65536);
    const float v0 = sv[j], v1 = sv[j + 1], v2 = sv[j + 2], v3 = sv[j + 3];
    acc.x += v0 * a0.x + v1 * a1.x + v2 * a2.x + v3 * a3.x;
    acc.y += v0 * a0.y + v1 * a1.y + v2 * a2.y + v3 * a3.y;
    acc.z += v0 * a0.z + v1 * a1.z + v2 * a2.z + v3 * a3.z;
    acc.w += v0 * a0.w + v1 * a1.w + v2 * a2.w + v3 * a3.w;
  }
  for (; j < nnz; ++j) {
    const float4 a0 = *(const float4*)(wb + (long)si[j] * 65536);
    const float v0 = sv[j];
    acc.x += v0 * a0.x; acc.y += v0 * a0.y; acc.z += v0 * a0.z; acc.w += v0 * a0.w;
  }
  const float4 bb = *(const float4*)(b2b + (long)h * 65536 + n0 + tid * 4);
  float4 o = {acc.x + bb.x, acc.y + bb.y, acc.z + bb.z, acc.w + bb.w};
  *(float4*)(biasb + (long)h * 65536 + n0 + tid * 4) = o;
}

// ---------------- m97-style 128x128 GEMM (kept for small matmuls)
// EPI: 0 = f32 out +bias
template <int EPI>
__global__ __launch_bounds__(256) void gemm_bt(
    const u16* __restrict__ A, const u16* __restrict__ BT, void* __restrict__ Cv,
    const float* __restrict__ bias, const float* __restrict__ R, int K, long sA,
    long sBT, long sC, long sBias, int ldc) {
  __shared__ u16 smA[128 * 32];
  __shared__ u16 smB[128 * 32];
  const int tid = threadIdx.x;
  const int lane = tid & 63;
  const int wv = tid >> 6;
  const int wr = wv >> 1, wc = wv & 1;
  const long tm = (long)blockIdx.x * 128;
  const long tn = (long)blockIdx.y * 128;
  const int z = blockIdx.z;
  A += (long)z * sA;
  BT += (long)z * sBT;

  const u16* ga = A + (tm + (tid >> 2)) * (long)K + (tid & 3) * 8;
  const u16* gb = BT + (tn + (tid >> 2)) * (long)K + (tid & 3) * 8;
  const long rstep = 64L * K;
  u16* la = &smA[tid * 8];
  u16* lb = &smB[tid * 8];

  f32x4 acc[4][4];
#pragma unroll
  for (int m = 0; m < 4; ++m)
#pragma unroll
    for (int n = 0; n < 4; ++n) acc[m][n] = (f32x4){0.f, 0.f, 0.f, 0.f};

  for (int k0 = 0; k0 < K; k0 += 32) {
    GLDS16(ga + k0, la);
    GLDS16(ga + rstep + k0, la + 64 * 32);
    GLDS16(gb + k0, lb);
    GLDS16(gb + rstep + k0, lb + 64 * 32);
    __syncthreads();
    s16x8 af[4], bf[4];
    const int ka = (lane >> 4) * 8;
    const int ra = wr * 64 + (lane & 15);
    const int rb = wc * 64 + (lane & 15);
#pragma unroll
    for (int m = 0; m < 4; ++m) af[m] = *(const s16x8*)&smA[(ra + m * 16) * 32 + ka];
#pragma unroll
    for (int n = 0; n < 4; ++n) bf[n] = *(const s16x8*)&smB[(rb + n * 16) * 32 + ka];
#pragma unroll
    for (int m = 0; m < 4; ++m)
#pragma unroll
      for (int n = 0; n < 4; ++n) acc[m][n] = mfma16(af[m], bf[n], acc[m][n]);
    __syncthreads();
  }

  const long crow0 = tm + wr * 64 + ((lane >> 4) * 4);
  const long ccol0 = tn + wc * 64 + (lane & 15);
#pragma unroll
  for (int m = 0; m < 4; ++m) {
#pragma unroll
    for (int n = 0; n < 4; ++n) {
#pragma unroll
      for (int i = 0; i < 4; ++i) {
        const long row = crow0 + m * 16 + i;
        const long col = ccol0 + n * 16;
        float v = acc[m][n][i] + bias[(long)z * sBias + col];
        if constexpr (EPI == 0) {
          ((float*)Cv)[(long)z * sC + row * ldc + col] = v;
        }
      }
    }
  }
}

// ---------------- merged QKV projection (batch 0): z = sel*8 + h
__global__ __launch_bounds__(256) void qkv_gemm(
    const u16* __restrict__ src0b, const u16* __restrict__ qwT,
    const u16* __restrict__ kwT, const u16* __restrict__ vwT,
    const float* __restrict__ qb, const float* __restrict__ kb,
    const float* __restrict__ vb, u16* __restrict__ q0, u16* __restrict__ k0,
    u16* __restrict__ v0T) {
  __shared__ u16 smA[128 * 32];
  __shared__ u16 smB[128 * 32];
  const int tid = threadIdx.x;
  const int lane = tid & 63;
  const int wv = tid >> 6;
  const int wr = wv >> 1, wc = wv & 1;
  const long tm = (long)blockIdx.x * 128;
  const int z = blockIdx.z, sel = z >> 3, h = z & 7;
  const int K = D_;
  const u16* BT = (sel == 0 ? qwT : (sel == 1 ? kwT : vwT)) + (long)h * DQ_ * D_;
  const float* bias = (sel == 0 ? qb : (sel == 1 ? kb : vb)) + h * DQ_;

  const u16* ga = src0b + (tm + (tid >> 2)) * (long)K + (tid & 3) * 8;
  const u16* gb = BT + (long)(tid >> 2) * K + (tid & 3) * 8;
  const long rstep = 64L * K;
  u16* la = &smA[tid * 8];
  u16* lb = &smB[tid * 8];

  f32x4 acc[4][4];
#pragma unroll
  for (int m = 0; m < 4; ++m)
#pragma unroll
    for (int n = 0; n < 4; ++n) acc[m][n] = (f32x4){0.f, 0.f, 0.f, 0.f};

  for (int k0_ = 0; k0_ < K; k0_ += 32) {
    GLDS16(ga + k0_, la);
    GLDS16(ga + rstep + k0_, la + 64 * 32);
    GLDS16(gb + k0_, lb);
    GLDS16(gb + rstep + k0_, lb + 64 * 32);
    __syncthreads();
    s16x8 af[4], bf[4];
    const int ka = (lane >> 4) * 8;
    const int ra = wr * 64 + (lane & 15);
    const int rb = wc * 64 + (lane & 15);
#pragma unroll
    for (int m = 0; m < 4; ++m) af[m] = *(const s16x8*)&smA[(ra + m * 16) * 32 + ka];
#pragma unroll
    for (int n = 0; n < 4; ++n) bf[n] = *(const s16x8*)&smB[(rb + n * 16) * 32 + ka];
#pragma unroll
    for (int m = 0; m < 4; ++m)
#pragma unroll
      for (int n = 0; n < 4; ++n) acc[m][n] = mfma16(af[m], bf[n], acc[m][n]);
    __syncthreads();
  }

  const long crow0 = tm + wr * 64 + ((lane >> 4) * 4);
  const long ccol0 = wc * 64 + (lane & 15);
#pragma unroll
  for (int m = 0; m < 4; ++m) {
#pragma unroll
    for (int n = 0; n < 4; ++n) {
#pragma unroll
      for (int i = 0; i < 4; ++i) {
        const long row = crow0 + m * 16 + i;
        const long col = ccol0 + n * 16;
        const float v = acc[m][n][i] + bias[col];
        if (sel < 2) {
          u16* o = (sel == 0 ? q0 : k0) + (long)h * L_ * DQ_;
          o[row * DQ_ + col] = f2bf(v);
        } else {
          v0T[(long)h * DQ_ * L_ + col * L_ + row] = f2bf(v);
        }
      }
    }
  }
}

// ---------------- 8-phase 256xBN deep-pipelined GEMM (T1+T2+T4+T5)
// A [M][K] bf16, BT [N][K] bf16. BK=64, 8 waves (2Mx4N), dbuf LDS.
// EPI: 1 = bf16 out relu(+bias); 4 = f32 out +bias +residual (in-place ok)
template <int BN, int EPI>
__global__ __launch_bounds__(512, 2) void gemm8p(
    const u16* __restrict__ A, const u16* __restrict__ BT, void* __restrict__ Cv,
    const float* __restrict__ bias, const float* __restrict__ R, int M, int N,
    int K, int ldc) {
  extern __shared__ char lds[];
  constexpr int NR = BN / 64;               // B frags per wave (4 or 2)
  constexpr int NHB = BN / 128;             // B half-tiles (2 or 1)
  constexpr int BUF = 32768 + BN * 128;     // bytes per K-tile buffer
  constexpr int WST = (NHB == 2) ? 4 : 2;   // steady-state vmcnt
  const int tid = threadIdx.x;
  const int lane = tid & 63;
  const int w = tid >> 6;
  const int wr = w >> 2, wc = w & 3;

  // XCD-aware swizzle (grid divisible by 8 for our shapes)
  const int total = gridDim.x;
  int bid = blockIdx.x;
  int s = ((total & 7) == 0) ? ((bid & 7) * (total >> 3) + (bid >> 3)) : bid;
  const int gn = N / BN;
  const long tm = (long)(s / gn) * 256;
  const long tn = (long)(s % gn) * BN;
  const int NT = K >> 6;

  // stage one 128x64 half-tile (2 x global_load_lds / thread), pre-swizzled src
  auto stageA = [&](int half, int t) {
    char* hb = lds + (long)(t & 1) * BUF + half * 16384;
    const u16* g = A + (tm + half * 128) * (long)K + (long)t * 64;
#pragma unroll
    for (int j = 0; j < 2; ++j) {
      const int idx = j * 512 + tid;
      const int r = idx >> 3;
      const int c16 = (idx & 7) ^ (r & 7);
      GLDS16(g + (long)r * K + c16 * 8, hb + idx * 16);
    }
  };
  auto stageB = [&](int half, int t) {
    char* hb = lds + (long)(t & 1) * BUF + 32768 + half * 16384;
    const u16* g = BT + (tn + half * 128) * (long)K + (long)t * 64;
#pragma unroll
    for (int j = 0; j < 2; ++j) {
      const int idx = j * 512 + tid;
      const int r = idx >> 3;
      const int c16 = (idx & 7) ^ (r & 7);
      GLDS16(g + (long)r * K + c16 * 8, hb + idx * 16);
    }
  };

  // prologue: tile0 (A0,A1,B0[,B1]) + tile1 B halves; land tile0, keep tile1-B in flight
  stageA(0, 0);
  stageA(1, 0);
  stageB(0, 0);
  if (NHB == 2) stageB(1, 0);
  stageB(0, 1);
  if (NHB == 2) stageB(1, 1);
  asm volatile("s_waitcnt vmcnt(%0)" ::"n"(WST) : "memory");
  __builtin_amdgcn_s_barrier();

  f32x4 acc[8][NR];
#pragma unroll
  for (int m = 0; m < 8; ++m)
#pragma unroll
    for (int n = 0; n < NR; ++n) acc[m][n] = (f32x4){0.f, 0.f, 0.f, 0.f};

  const int lk = (lane >> 4) * 16;  // k byte offset within 128B row
  const int lr = lane & 15;

  for (int t = 0; t < NT; ++t) {
    const char* bp = lds + (long)(t & 1) * BUF;
    s16x8 bfr[NR][2];
#pragma unroll
    for (int p = 0; p < 4; ++p) {
      // ds-reads for this phase
      if (p == 0) {
#pragma unroll
        for (int ni = 0; ni < NR; ++ni) {
          const int brow = wc * (BN / 4) + ni * 16 + lr;
#pragma unroll
          for (int ks = 0; ks < 2; ++ks) {
            const int kb = (ks * 64 + lk) ^ ((brow & 7) << 4);
            bfr[ni][ks] = *(const s16x8*)(bp + 32768 + brow * 128 + kb);
          }
        }
      }
      s16x8 afr[2][2];
#pragma unroll
      for (int rI = 0; rI < 2; ++rI) {
        const int arow = wr * 128 + (2 * p + rI) * 16 + lr;
#pragma unroll
        for (int ks = 0; ks < 2; ++ks) {
          const int kb = (ks * 64 + lk) ^ ((arow & 7) << 4);
          afr[rI][ks] = *(const s16x8*)(bp + arow * 128 + kb);
        }
      }
      // stage slot (derived-safe map: A(t+1) at p0/p1, B(t+2) at p2/p3)
      if (p == 0) {
        if (t + 1 < NT) stageA(0, t + 1);
      } else if (p == 1) {
        if (t + 1 < NT) stageA(1, t + 1);
      } else if (p == 2) {
        if (t + 2 < NT) stageB(0, t + 2);
      } else {
        if (NHB == 2 && t + 2 < NT) stageB(1, t + 2);
      }
      __builtin_amdgcn_s_barrier();
      __builtin_amdgcn_s_setprio(1);
#pragma unroll
      for (int rI = 0; rI < 2; ++rI)
#pragma unroll
        for (int ni = 0; ni < NR; ++ni)
#pragma unroll
          for (int ks = 0; ks < 2; ++ks)
            acc[2 * p + rI][ni] = mfma16(afr[rI][ks], bfr[ni][ks], acc[2 * p + rI][ni]);
      __builtin_amdgcn_s_setprio(0);
      if (p == 3) {
        if (t + 2 < NT) {
          asm volatile("s_waitcnt vmcnt(%0)" ::"n"(WST) : "memory");
        } else if (t + 1 < NT) {
          asm volatile("s_waitcnt vmcnt(0)" ::: "memory");
        }
      }
      __builtin_amdgcn_s_barrier();
    }
  }

  const long crow0 = tm + wr * 128 + ((lane >> 4) * 4);
  const long ccol0 = tn + wc * (BN / 4) + lr;
#pragma unroll
  for (int m = 0; m < 8; ++m) {
#pragma unroll
    for (int n = 0; n < NR; ++n) {
#pragma unroll
      for (int i = 0; i < 4; ++i) {
        const long row = crow0 + m * 16 + i;
        const long col = ccol0 + n * 16;
        const float v = acc[m][n][i] + bias[col];
        if constexpr (EPI == 1) {
          ((u16*)Cv)[row * (long)ldc + col] = f2bf(fmaxf(v, 0.f));
        } else {
          ((float*)Cv)[row * (long)ldc + col] = v + R[row * (long)ldc + col];
        }
      }
    }
  }
}

// ---------------- fused attention for batch 0, one wave per (head, 16-row tile)
__global__ __launch_bounds__(64) void attn_kernel(
    const u16* __restrict__ q0, const u16* __restrict__ k0,
    const u16* __restrict__ vT, const float* __restrict__ biasb,
    const int* __restrict__ mask0, u16* __restrict__ hidden) {
  const int lane = threadIdx.x;
  const int h = blockIdx.y;
  const int r0 = blockIdx.x * 16;
  const u16* q = q0 + (long)h * L_ * DQ_;
  const u16* k = k0 + (long)h * L_ * DQ_;
  const u16* v = vT + (long)h * DQ_ * L_;
  const int lg = lane >> 4;
  const int ll = lane & 15;

  s16x8 aq[4];
#pragma unroll
  for (int kk = 0; kk < 4; ++kk)
    aq[kk] = *(const s16x8*)(q + (long)(r0 + ll) * DQ_ + kk * 32 + lg * 8);

  float sc[16][4];
  const float scale = 0.08838834764831845f;
#pragma unroll
  for (int t = 0; t < 16; ++t) {
    f32x4 a = {0.f, 0.f, 0.f, 0.f};
#pragma unroll
    for (int kk = 0; kk < 4; ++kk) {
      s16x8 bf = *(const s16x8*)(k + (long)(t * 16 + ll) * DQ_ + kk * 32 + lg * 8);
      a = mfma16(aq[kk], bf, a);
    }
#pragma unroll
    for (int i = 0; i < 4; ++i) {
      const int row = r0 + lg * 4 + i;
      const int col = t * 16 + ll;
      float s = a[i] * scale;
      if (mask0[row * L_ + col] != 0) s = 1e-9f;
      sc[t][i] = s;
    }
  }
#pragma unroll
  for (int i = 0; i < 4; ++i) {
    float mx = sc[0][i];
#pragma unroll
    for (int t = 1; t < 16; ++t) mx = fmaxf(mx, sc[t][i]);
#pragma unroll
    for (int d = 1; d < 16; d <<= 1) mx = fmaxf(mx, __shfl_xor(mx, d));
    float sum = 0.f;
#pragma unroll
    for (int t = 0; t < 16; ++t) {
      const float e = __expf(sc[t][i] - mx);
      sc[t][i] = e;
      sum += e;
    }
#pragma unroll
    for (int d = 1; d < 16; d <<= 1) sum += __shfl_xor(sum, d);
    const float inv = 1.f / sum;
    const int row = r0 + lg * 4 + i;
#pragma unroll
    for (int t = 0; t < 16; ++t)
      sc[t][i] = sc[t][i] * inv + biasb[(long)h * 65536 + (long)row * 256 + t * 16 + ll];
  }
  __shared__ float sm[16 * 256];
#pragma unroll
  for (int t = 0; t < 16; ++t)
#pragma unroll
    for (int i = 0; i < 4; ++i)
      sm[(lg * 4 + i) * 256 + t * 16 + ll] = sc[t][i];
  __syncthreads();
  s16x8 af[8];
#pragma unroll
  for (int kk = 0; kk < 8; ++kk) {
    const float* ap = &sm[ll * 256 + kk * 32 + lg * 8];
    s16x8 t8;
#pragma unroll
    for (int j = 0; j < 8; ++j) t8[j] = (short)f2bf(ap[j]);
    af[kk] = t8;
  }
#pragma unroll
  for (int n = 0; n < 8; ++n) {
    f32x4 a = {0.f, 0.f, 0.f, 0.f};
#pragma unroll
    for (int kk = 0; kk < 8; ++kk) {
      s16x8 bf = *(const s16x8*)(v + (long)(n * 16 + ll) * 256 + kk * 32 + lg * 8);
      a = mfma16(af[kk], bf, a);
    }
#pragma unroll
    for (int i = 0; i < 4; ++i) {
      const int row = r0 + lg * 4 + i;
      const int col = n * 16 + ll;
      hidden[(long)row * 1024 + h * 128 + col] = f2bf(a[i]);
    }
  }
}

// ---------------- layernorm over D=1024; optional add of attn row (row%L); dual out
__global__ __launch_bounds__(256) void ln_kernel(
    const float* __restrict__ in0, const float* __restrict__ add1,
    const float* __restrict__ g, const float* __restrict__ bb,
    float* __restrict__ outf, u16* __restrict__ outb) {
  const int tid = threadIdx.x;
  const long row = blockIdx.x;
  float4 v = ((const float4*)(in0 + row * D_))[tid];
  if (add1) {
    const float4 u = ((const float4*)(add1 + (row & (L_ - 1)) * D_))[tid];
    v.x += u.x; v.y += u.y; v.z += u.z; v.w += u.w;
  }
  float s = v.x + v.y + v.z + v.w;
  float q = v.x * v.x + v.y * v.y + v.z * v.z + v.w * v.w;
#pragma unroll
  for (int d = 1; d < 64; d <<= 1) { s += __shfl_xor(s, d); q += __shfl_xor(q, d); }
  __shared__ float ss[4], sq[4];
  const int wv = tid >> 6;
  if ((tid & 63) == 0) { ss[wv] = s; sq[wv] = q; }
  __syncthreads();
  s = ss[0] + ss[1] + ss[2] + ss[3];
  q = sq[0] + sq[1] + sq[2] + sq[3];
  const float mu = s * (1.f / D_);
  const float var = q * (1.f / D_) - mu * mu;
  const float rs = rsqrtf(var + 1e-5f);
  const float4 gv = ((const float4*)g)[tid];
  const float4 bv = ((const float4*)bb)[tid];
  float4 o;
  o.x = (v.x - mu) * rs * gv.x + bv.x;
  o.y = (v.y - mu) * rs * gv.y + bv.y;
  o.z = (v.z - mu) * rs * gv.z + bv.z;
  o.w = (v.w - mu) * rs * gv.w + bv.w;
  ((float4*)(outf + row * D_))[tid] = o;
  if (outb) {
    uint2 pk;
    pk.x = (unsigned)f2bf(o.x) | ((unsigned)f2bf(o.y) << 16);
    pk.y = (unsigned)f2bf(o.z) | ((unsigned)f2bf(o.w) << 16);
    *(uint2*)(outb + row * D_ + tid * 4) = pk;
  }
}

extern "C" void kernel_launch(void* const* d_in, const int* in_sizes, int n_in,
                              void* d_out, int out_size, void* d_ws, size_t ws_size,
                              hipStream_t stream) {
  (void)in_sizes; (void)n_in; (void)out_size; (void)ws_size;
  const float* src = (const float*)d_in[0];
  const float* sf = (const float*)d_in[1];
  const int* mask = (const int*)d_in[2];
  const float* qw = (const float*)d_in[3];
  const float* qb = (const float*)d_in[4];
  const float* kw = (const float*)d_in[5];
  const float* kb = (const float*)d_in[6];
  const float* vw = (const float*)d_in[7];
  const float* vb = (const float*)d_in[8];
  const float* b1w = (const float*)d_in[9];
  const float* b1b = (const float*)d_in[10];
  const float* b2w = (const float*)d_in[11];
  const float* b2b = (const float*)d_in[12];
  const float* ow = (const float*)d_in[13];
  const float* ob = (const float*)d_in[14];
  const float* ln1g = (const float*)d_in[15];
  const float* ln1b = (const float*)d_in[16];
  const float* ln2g = (const float*)d_in[17];
  const float* ln2b = (const float*)d_in[18];
  const float* w1 = (const float*)d_in[19];
  const float* bf1 = (const float*)d_in[20];
  const float* w2 = (const float*)d_in[21];
  const float* bf2 = (const float*)d_in[22];
  float* out = (float*)d_out;

  char* ws = (char*)d_ws;
  size_t off = 0;
  auto alloc = [&](size_t bytes) {
    void* p = ws + off;
    off += (bytes + 255) & ~(size_t)255;
    return p;
  };
  u16* qwT = (u16*)alloc((size_t)H_ * DQ_ * D_ * 2);
  u16* kwT = (u16*)alloc((size_t)H_ * DQ_ * D_ * 2);
  u16* vwT = (u16*)alloc((size_t)H_ * DQ_ * D_ * 2);
  u16* owT = (u16*)alloc((size_t)D_ * D_ * 2);
  u16* w1T = (u16*)alloc((size_t)DF_ * D_ * 2);
  u16* w2T = (u16*)alloc((size_t)D_ * DF_ * 2);
  u16* src0b = (u16*)alloc((size_t)L_ * D_ * 2);
  u16* q0 = (u16*)alloc((size_t)H_ * L_ * DQ_ * 2);
  u16* k0 = (u16*)alloc((size_t)H_ * L_ * DQ_ * 2);
  u16* v0T = (u16*)alloc((size_t)H_ * DQ_ * L_ * 2);
  float* nzv = (float*)alloc((size_t)H_ * DM_ * 4);
  int* nzi = (int*)alloc((size_t)H_ * DM_ * 4);
  int* nzcnt = (int*)alloc(256);
  float* biasb = (float*)alloc((size_t)H_ * L_ * L_ * 4);
  u16* hidden = (u16*)alloc((size_t)L_ * H_ * DQ_ * 2);
  float* attnvec = (float*)alloc((size_t)L_ * D_ * 4);
  float* xf = (float*)alloc((size_t)B_ * L_ * D_ * 4);
  u16* xb = (u16*)alloc((size_t)B_ * L_ * D_ * 2);
  u16* ffnh = (u16*)alloc((size_t)B_ * L_ * DF_ * 2);

  hipFuncSetAttribute((const void*)gemm8p<256, 1>,
                      hipFuncAttributeMaxDynamicSharedMemorySize, 131072);
  hipFuncSetAttribute((const void*)gemm8p<128, 4>,
                      hipFuncAttributeMaxDynamicSharedMemorySize, 98304);

  const dim3 b256(256);
  // weight transpose+convert
  tconv_qkv<<<dim3(DQ_ / 32, D_ / 32, 24), b256, 0, stream>>>(qw, kw, vw, qwT, kwT, vwT);
  tconv<<<dim3(D_ / 32, D_ / 32, 1), b256, 0, stream>>>(ow, owT, D_, D_, 0, 0);
  tconv<<<dim3(DF_ / 32, D_ / 32, 1), b256, 0, stream>>>(w1, w1T, D_, DF_, 0, 0);
  tconv<<<dim3(D_ / 32, DF_ / 32, 1), b256, 0, stream>>>(w2, w2T, DF_, D_, 0, 0);
  conv_bf16<<<dim3(L_ * D_ / 1024), b256, 0, stream>>>(src, src0b);

  // bias MLP (only sf[0] needed) + big GEMV over b2w with zero-row skipping
  hid_kernel<<<dim3(H_), b256, 0, stream>>>(sf, b1w, b1b, nzv, nzi, nzcnt);
  bias_gemv<<<dim3(64, H_), b256, 0, stream>>>(nzv, nzi, nzcnt, b2w, b2b, biasb);

  // merged QKV projections (batch 0)
  qkv_gemm<<<dim3(2, 1, 24), b256, 0, stream>>>(src0b, qwT, kwT, vwT, qb, kb, vb,
                                                q0, k0, v0T);

  // attention (b=0), writes hidden [L][H*DQ] bf16
  attn_kernel<<<dim3(16, H_), dim3(64), 0, stream>>>(q0, k0, v0T, biasb, mask, hidden);

  // attn out projection -> attnvec [L][D] f32
  gemm_bt<0><<<dim3(2, 8, 1), b256, 0, stream>>>(
      hidden, owT, attnvec, ob, nullptr, D_, 0, 0, 0, 0, D_);

  // LN1: x = LN(src + attn[None]) -> xf (f32) + xb (bf16)
  ln_kernel<<<dim3(B_ * L_), b256, 0, stream>>>(src, attnvec, ln1g, ln1b, xf, xb);

  // FFN1: relu(x @ w1 + bf1) -> ffnh bf16   [8192 x 4096 x 1024]
  gemm8p<256, 1><<<dim3(512), dim3(512), 131072, stream>>>(
      xb, w1T, ffnh, bf1, nullptr, B_ * L_, DF_, D_, DF_);
  // FFN2: xf = ffnh @ w2 + bf2 + xf (residual fused, in-place) [8192 x 1024 x 4096]
  gemm8p<128, 4><<<dim3(256), dim3(512), 98304, stream>>>(
      ffnh, w2T, xf, bf2, xf, B_ * L_, D_, DF_, D_);

  // LN2 -> d_out
  ln_kernel<<<dim3(B_ * L_), b256, 0, stream>>>(xf, nullptr, ln2g, ln2b, out, nullptr);
}

// Round 3
// 329.032 us; speedup vs baseline: 1.5344x; 1.1069x over previous
//
#include <hip/hip_runtime.h>

typedef unsigned short u16;
typedef short s16x8 __attribute__((ext_vector_type(8)));
typedef u16 u16x4 __attribute__((ext_vector_type(4)));
typedef float f32x4 __attribute__((ext_vector_type(4)));

#define B_ 32
#define L_ 256
#define D_ 1024
#define H_ 8
#define DQ_ 128
#define DS_ 64
#define DM_ 256
#define DF_ 4096

__device__ __forceinline__ u16 f2bf(float f) {
  unsigned u = __float_as_uint(f);
  unsigned r = (u + 0x7FFFu + ((u >> 16) & 1u)) >> 16;
  return (u16)r;
}
__device__ __forceinline__ float bf2f(u16 x) {
  return __uint_as_float(((unsigned)x) << 16);
}

__device__ __forceinline__ f32x4 mfma16(s16x8 a, s16x8 b, f32x4 c) {
  return __builtin_amdgcn_mfma_f32_16x16x32_bf16(a, b, c, 0, 0, 0);
}

#define GLDS16(g, l)                                                        \
  __builtin_amdgcn_global_load_lds(                                         \
      (__attribute__((address_space(1))) const void*)(g),                   \
      (__attribute__((address_space(3))) void*)(l), 16, 0, 0)

// ---------------- 32x32 transpose+convert tile helper
__device__ __forceinline__ void tile_tr(const float* __restrict__ ip,
                                        u16* __restrict__ op, int K, int N,
                                        int bx, int by, float (*t)[33], int tid) {
  const int tx = tid & 31, ty = tid >> 5;
  const long n0 = (long)bx * 32, k0 = (long)by * 32;
#pragma unroll
  for (int i = 0; i < 4; ++i)
    t[ty + i * 8][tx] = ip[(k0 + ty + i * 8) * (long)N + n0 + tx];
  __syncthreads();
#pragma unroll
  for (int i = 0; i < 4; ++i)
    op[(n0 + ty + i * 8) * (long)K + k0 + tx] = f2bf(t[tx][ty + i * 8]);
}

// ---------------- phase 1 mega-kernel: all weight transposes + src conv + hid
// grid: [0,3072) qkvT | [3072,4096) owT | [4096,8192) w1T | [8192,12288) w2T |
//       [12288,12544) conv src b0 | [12544,12552) hid
__global__ __launch_bounds__(256) void prep(
    const float* __restrict__ qw, const float* __restrict__ kw,
    const float* __restrict__ vw, const float* __restrict__ ow,
    const float* __restrict__ w1, const float* __restrict__ w2,
    const float* __restrict__ src, const float* __restrict__ sf,
    const float* __restrict__ b1w, const float* __restrict__ b1b,
    u16* __restrict__ qwT, u16* __restrict__ kwT, u16* __restrict__ vwT,
    u16* __restrict__ owT, u16* __restrict__ w1T, u16* __restrict__ w2T,
    u16* __restrict__ src0b, float* __restrict__ nzv, int* __restrict__ nzi,
    int* __restrict__ nzcnt) {
  const int b = blockIdx.x;
  const int tid = threadIdx.x;
  __shared__ float t[32][33];
  __shared__ float s_sf[DS_];
  __shared__ int wcnt[4];
  if (b < 3072) {
    const int z = b >> 7, rem = b & 127;
    const int sel = z >> 3, h = z & 7;
    const float* ip = (sel == 0 ? qw : (sel == 1 ? kw : vw)) + (long)h * D_ * DQ_;
    u16* op = (sel == 0 ? qwT : (sel == 1 ? kwT : vwT)) + (long)h * DQ_ * D_;
    tile_tr(ip, op, D_, DQ_, rem & 3, rem >> 2, t, tid);
  } else if (b < 4096) {
    const int rem = b - 3072;
    tile_tr(ow, owT, D_, D_, rem & 31, rem >> 5, t, tid);
  } else if (b < 8192) {
    const int rem = b - 4096;
    tile_tr(w1, w1T, D_, DF_, rem & 127, rem >> 7, t, tid);
  } else if (b < 12288) {
    const int rem = b - 8192;
    tile_tr(w2, w2T, DF_, D_, rem & 31, rem >> 5, t, tid);
  } else if (b < 12544) {
    const int rem = b - 12288;
    const int i = (rem * 256 + tid) * 4;
    float4 v = *(const float4*)(src + i);
    u16x4 o = {f2bf(v.x), f2bf(v.y), f2bf(v.z), f2bf(v.w)};
    *(u16x4*)(src0b + i) = o;
  } else {
    const int h = b - 12544;
    if (tid < DS_) s_sf[tid] = sf[tid];
    __syncthreads();
    float a = b1b[h * DM_ + tid];
    const float* wp = b1w + (long)h * DS_ * DM_ + tid;
#pragma unroll 8
    for (int s = 0; s < DS_; ++s) a += s_sf[s] * wp[s * DM_];
    a = fmaxf(a, 0.f);
    const unsigned long long bal = __ballot(a > 0.f);
    const int lane = tid & 63, wv = tid >> 6;
    const int pc = __popcll(bal);
    if (lane == 0) wcnt[wv] = pc;
    __syncthreads();
    int base = 0;
    for (int i = 0; i < wv; ++i) base += wcnt[i];
    const int pos = base + __popcll(bal & ((1ull << lane) - 1ull));
    if (a > 0.f) { nzv[h * DM_ + pos] = a; nzi[h * DM_ + pos] = tid; }
    if (tid == 255) nzcnt[h] = base + pc;
  }
}

// ---------------- phase 2: bias_gemv (blocks 0..511) || QKV projection (512..559)
__global__ __launch_bounds__(256) void phase2(
    const float* __restrict__ nzv, const int* __restrict__ nzi,
    const int* __restrict__ nzcnt, const float* __restrict__ b2w,
    const float* __restrict__ b2b, float* __restrict__ biasb,
    const u16* __restrict__ src0b, const u16* __restrict__ qwT,
    const u16* __restrict__ kwT, const u16* __restrict__ vwT,
    const float* __restrict__ qb, const float* __restrict__ kb,
    const float* __restrict__ vb, u16* __restrict__ q0, u16* __restrict__ k0,
    u16* __restrict__ v0T) {
  const int b = blockIdx.x;
  const int tid = threadIdx.x;
  __shared__ float sv[DM_];
  __shared__ int si[DM_];
  __shared__ u16 smA[128 * 32];
  __shared__ u16 smB[128 * 32];
  if (b < 512) {
    const int h = b >> 6;
    const int n0 = (b & 63) << 10;
    const int nnz = nzcnt[h];
    if (tid < DM_) { sv[tid] = nzv[h * DM_ + tid]; si[tid] = nzi[h * DM_ + tid]; }
    __syncthreads();
    const float* wb = b2w + (long)h * DM_ * 65536 + n0 + tid * 4;
    float4 acc = {0.f, 0.f, 0.f, 0.f};
    int j = 0;
    for (; j + 4 <= nnz; j += 4) {
      const float4 a0 = *(const float4*)(wb + (long)si[j] * 65536);
      const float4 a1 = *(const float4*)(wb + (long)si[j + 1] * 65536);
      const float4 a2 = *(const float4*)(wb + (long)si[j + 2] * 65536);
      const float4 a3 = *(const float4*)(wb + (long)si[j + 3] * 65536);
      const float v0 = sv[j], v1 = sv[j + 1], v2 = sv[j + 2], v3 = sv[j + 3];
      acc.x += v0 * a0.x + v1 * a1.x + v2 * a2.x + v3 * a3.x;
      acc.y += v0 * a0.y + v1 * a1.y + v2 * a2.y + v3 * a3.y;
      acc.z += v0 * a0.z + v1 * a1.z + v2 * a2.z + v3 * a3.z;
      acc.w += v0 * a0.w + v1 * a1.w + v2 * a2.w + v3 * a3.w;
    }
    for (; j < nnz; ++j) {
      const float4 a0 = *(const float4*)(wb + (long)si[j] * 65536);
      const float v0 = sv[j];
      acc.x += v0 * a0.x; acc.y += v0 * a0.y; acc.z += v0 * a0.z; acc.w += v0 * a0.w;
    }
    const float4 bb = *(const float4*)(b2b + (long)h * 65536 + n0 + tid * 4);
    float4 o = {acc.x + bb.x, acc.y + bb.y, acc.z + bb.z, acc.w + bb.w};
    *(float4*)(biasb + (long)h * 65536 + n0 + tid * 4) = o;
  } else {
    const int r = b - 512;
    const int z = r >> 1, sel = z >> 3, h = z & 7;
    const long tm = (long)(r & 1) * 128;
    const int K = D_;
    const u16* BT = (sel == 0 ? qwT : (sel == 1 ? kwT : vwT)) + (long)h * DQ_ * D_;
    const float* bias = (sel == 0 ? qb : (sel == 1 ? kb : vb)) + h * DQ_;
    const int lane = tid & 63;
    const int wv = tid >> 6;
    const int wr = wv >> 1, wc = wv & 1;
    const u16* ga = src0b + (tm + (tid >> 2)) * (long)K + (tid & 3) * 8;
    const u16* gb = BT + (long)(tid >> 2) * K + (tid & 3) * 8;
    const long rstep = 64L * K;
    u16* la = &smA[tid * 8];
    u16* lb = &smB[tid * 8];
    f32x4 acc[4][4];
#pragma unroll
    for (int m = 0; m < 4; ++m)
#pragma unroll
      for (int n = 0; n < 4; ++n) acc[m][n] = (f32x4){0.f, 0.f, 0.f, 0.f};
    for (int k0_ = 0; k0_ < K; k0_ += 32) {
      GLDS16(ga + k0_, la);
      GLDS16(ga + rstep + k0_, la + 64 * 32);
      GLDS16(gb + k0_, lb);
      GLDS16(gb + rstep + k0_, lb + 64 * 32);
      __syncthreads();
      s16x8 af[4], bf[4];
      const int ka = (lane >> 4) * 8;
      const int ra = wr * 64 + (lane & 15);
      const int rb = wc * 64 + (lane & 15);
#pragma unroll
      for (int m = 0; m < 4; ++m) af[m] = *(const s16x8*)&smA[(ra + m * 16) * 32 + ka];
#pragma unroll
      for (int n = 0; n < 4; ++n) bf[n] = *(const s16x8*)&smB[(rb + n * 16) * 32 + ka];
#pragma unroll
      for (int m = 0; m < 4; ++m)
#pragma unroll
        for (int n = 0; n < 4; ++n) acc[m][n] = mfma16(af[m], bf[n], acc[m][n]);
      __syncthreads();
    }
    const long crow0 = tm + wr * 64 + ((lane >> 4) * 4);
    const long ccol0 = wc * 64 + (lane & 15);
#pragma unroll
    for (int m = 0; m < 4; ++m) {
#pragma unroll
      for (int n = 0; n < 4; ++n) {
#pragma unroll
        for (int i = 0; i < 4; ++i) {
          const long row = crow0 + m * 16 + i;
          const long col = ccol0 + n * 16;
          const float v = acc[m][n][i] + bias[col];
          if (sel < 2) {
            u16* o = (sel == 0 ? q0 : k0) + (long)h * L_ * DQ_;
            o[row * DQ_ + col] = f2bf(v);
          } else {
            v0T[(long)h * DQ_ * L_ + col * L_ + row] = f2bf(v);
          }
        }
      }
    }
  }
}

// ---------------- m97-style 128x128 GEMM, EPI 0 = f32 out +bias (attn out proj)
__global__ __launch_bounds__(256) void gemm_bt(
    const u16* __restrict__ A, const u16* __restrict__ BT, float* __restrict__ C,
    const float* __restrict__ bias, int K, int ldc) {
  __shared__ u16 smA[128 * 32];
  __shared__ u16 smB[128 * 32];
  const int tid = threadIdx.x;
  const int lane = tid & 63;
  const int wv = tid >> 6;
  const int wr = wv >> 1, wc = wv & 1;
  const long tm = (long)blockIdx.x * 128;
  const long tn = (long)blockIdx.y * 128;

  const u16* ga = A + (tm + (tid >> 2)) * (long)K + (tid & 3) * 8;
  const u16* gb = BT + (tn + (tid >> 2)) * (long)K + (tid & 3) * 8;
  const long rstep = 64L * K;
  u16* la = &smA[tid * 8];
  u16* lb = &smB[tid * 8];

  f32x4 acc[4][4];
#pragma unroll
  for (int m = 0; m < 4; ++m)
#pragma unroll
    for (int n = 0; n < 4; ++n) acc[m][n] = (f32x4){0.f, 0.f, 0.f, 0.f};

  for (int k0 = 0; k0 < K; k0 += 32) {
    GLDS16(ga + k0, la);
    GLDS16(ga + rstep + k0, la + 64 * 32);
    GLDS16(gb + k0, lb);
    GLDS16(gb + rstep + k0, lb + 64 * 32);
    __syncthreads();
    s16x8 af[4], bf[4];
    const int ka = (lane >> 4) * 8;
    const int ra = wr * 64 + (lane & 15);
    const int rb = wc * 64 + (lane & 15);
#pragma unroll
    for (int m = 0; m < 4; ++m) af[m] = *(const s16x8*)&smA[(ra + m * 16) * 32 + ka];
#pragma unroll
    for (int n = 0; n < 4; ++n) bf[n] = *(const s16x8*)&smB[(rb + n * 16) * 32 + ka];
#pragma unroll
    for (int m = 0; m < 4; ++m)
#pragma unroll
      for (int n = 0; n < 4; ++n) acc[m][n] = mfma16(af[m], bf[n], acc[m][n]);
    __syncthreads();
  }

  const long crow0 = tm + wr * 64 + ((lane >> 4) * 4);
  const long ccol0 = tn + wc * 64 + (lane & 15);
#pragma unroll
  for (int m = 0; m < 4; ++m)
#pragma unroll
    for (int n = 0; n < 4; ++n)
#pragma unroll
      for (int i = 0; i < 4; ++i) {
        const long row = crow0 + m * 16 + i;
        const long col = ccol0 + n * 16;
        C[row * (long)ldc + col] = acc[m][n][i] + bias[col];
      }
}

// ---------------- 8-phase 256xBN deep-pipelined GEMM (T1+T2+T4+T5)
// EPI: 1 = bf16 out relu(+bias); 2 = bf16 out +bias +bf16 residual
template <int BN, int EPI>
__global__ __launch_bounds__(512, 2) void gemm8p(
    const u16* __restrict__ A, const u16* __restrict__ BT, void* __restrict__ Cv,
    const float* __restrict__ bias, const void* __restrict__ R, int M, int N,
    int K, int ldc) {
  extern __shared__ char lds[];
  constexpr int NR = BN / 64;
  constexpr int NHB = BN / 128;
  constexpr int BUF = 32768 + BN * 128;
  constexpr int WST = (NHB == 2) ? 4 : 2;
  const int tid = threadIdx.x;
  const int lane = tid & 63;
  const int w = tid >> 6;
  const int wr = w >> 2, wc = w & 3;

  const int total = gridDim.x;
  int bid = blockIdx.x;
  int s = ((total & 7) == 0) ? ((bid & 7) * (total >> 3) + (bid >> 3)) : bid;
  const int gn = N / BN;
  const long tm = (long)(s / gn) * 256;
  const long tn = (long)(s % gn) * BN;
  const int NT = K >> 6;

  auto stageA = [&](int half, int t) {
    char* hb = lds + (long)(t & 1) * BUF + half * 16384;
    const u16* g = A + (tm + half * 128) * (long)K + (long)t * 64;
#pragma unroll
    for (int j = 0; j < 2; ++j) {
      const int idx = j * 512 + tid;
      const int r = idx >> 3;
      const int c16 = (idx & 7) ^ (r & 7);
      GLDS16(g + (long)r * K + c16 * 8, hb + idx * 16);
    }
  };
  auto stageB = [&](int half, int t) {
    char* hb = lds + (long)(t & 1) * BUF + 32768 + half * 16384;
    const u16* g = BT + (tn + half * 128) * (long)K + (long)t * 64;
#pragma unroll
    for (int j = 0; j < 2; ++j) {
      const int idx = j * 512 + tid;
      const int r = idx >> 3;
      const int c16 = (idx & 7) ^ (r & 7);
      GLDS16(g + (long)r * K + c16 * 8, hb + idx * 16);
    }
  };

  stageA(0, 0);
  stageA(1, 0);
  stageB(0, 0);
  if (NHB == 2) stageB(1, 0);
  stageB(0, 1);
  if (NHB == 2) stageB(1, 1);
  asm volatile("s_waitcnt vmcnt(%0)" ::"n"(WST) : "memory");
  __builtin_amdgcn_s_barrier();

  f32x4 acc[8][NR];
#pragma unroll
  for (int m = 0; m < 8; ++m)
#pragma unroll
    for (int n = 0; n < NR; ++n) acc[m][n] = (f32x4){0.f, 0.f, 0.f, 0.f};

  const int lk = (lane >> 4) * 16;
  const int lr = lane & 15;

  for (int t = 0; t < NT; ++t) {
    const char* bp = lds + (long)(t & 1) * BUF;
    s16x8 bfr[NR][2];
#pragma unroll
    for (int p = 0; p < 4; ++p) {
      if (p == 0) {
#pragma unroll
        for (int ni = 0; ni < NR; ++ni) {
          const int brow = wc * (BN / 4) + ni * 16 + lr;
#pragma unroll
          for (int ks = 0; ks < 2; ++ks) {
            const int kb = (ks * 64 + lk) ^ ((brow & 7) << 4);
            bfr[ni][ks] = *(const s16x8*)(bp + 32768 + brow * 128 + kb);
          }
        }
      }
      s16x8 afr[2][2];
#pragma unroll
      for (int rI = 0; rI < 2; ++rI) {
        const int arow = wr * 128 + (2 * p + rI) * 16 + lr;
#pragma unroll
        for (int ks = 0; ks < 2; ++ks) {
          const int kb = (ks * 64 + lk) ^ ((arow & 7) << 4);
          afr[rI][ks] = *(const s16x8*)(bp + arow * 128 + kb);
        }
      }
      if (p == 0) {
        if (t + 1 < NT) stageA(0, t + 1);
      } else if (p == 1) {
        if (t + 1 < NT) stageA(1, t + 1);
      } else if (p == 2) {
        if (t + 2 < NT) stageB(0, t + 2);
      } else {
        if (NHB == 2 && t + 2 < NT) stageB(1, t + 2);
      }
      __builtin_amdgcn_s_barrier();
      __builtin_amdgcn_s_setprio(1);
#pragma unroll
      for (int rI = 0; rI < 2; ++rI)
#pragma unroll
        for (int ni = 0; ni < NR; ++ni)
#pragma unroll
          for (int ks = 0; ks < 2; ++ks)
            acc[2 * p + rI][ni] = mfma16(afr[rI][ks], bfr[ni][ks], acc[2 * p + rI][ni]);
      __builtin_amdgcn_s_setprio(0);
      if (p == 3) {
        if (t + 2 < NT) {
          asm volatile("s_waitcnt vmcnt(%0)" ::"n"(WST) : "memory");
        } else if (t + 1 < NT) {
          asm volatile("s_waitcnt vmcnt(0)" ::: "memory");
        }
      }
      __builtin_amdgcn_s_barrier();
    }
  }

  const long crow0 = tm + wr * 128 + ((lane >> 4) * 4);
  const long ccol0 = tn + wc * (BN / 4) + lr;
#pragma unroll
  for (int m = 0; m < 8; ++m) {
#pragma unroll
    for (int n = 0; n < NR; ++n) {
#pragma unroll
      for (int i = 0; i < 4; ++i) {
        const long row = crow0 + m * 16 + i;
        const long col = ccol0 + n * 16;
        const float v = acc[m][n][i] + bias[col];
        if constexpr (EPI == 1) {
          ((u16*)Cv)[row * (long)ldc + col] = f2bf(fmaxf(v, 0.f));
        } else {
          const float r = bf2f(((const u16*)R)[row * (long)ldc + col]);
          ((u16*)Cv)[row * (long)ldc + col] = f2bf(v + r);
        }
      }
    }
  }
}

// ---------------- fused attention for batch 0, one wave per (head, 16-row tile)
__global__ __launch_bounds__(64) void attn_kernel(
    const u16* __restrict__ q0, const u16* __restrict__ k0,
    const u16* __restrict__ vT, const float* __restrict__ biasb,
    const int* __restrict__ mask0, u16* __restrict__ hidden) {
  const int lane = threadIdx.x;
  const int h = blockIdx.y;
  const int r0 = blockIdx.x * 16;
  const u16* q = q0 + (long)h * L_ * DQ_;
  const u16* k = k0 + (long)h * L_ * DQ_;
  const u16* v = vT + (long)h * DQ_ * L_;
  const int lg = lane >> 4;
  const int ll = lane & 15;

  s16x8 aq[4];
#pragma unroll
  for (int kk = 0; kk < 4; ++kk)
    aq[kk] = *(const s16x8*)(q + (long)(r0 + ll) * DQ_ + kk * 32 + lg * 8);

  float sc[16][4];
  const float scale = 0.08838834764831845f;
#pragma unroll
  for (int t = 0; t < 16; ++t) {
    f32x4 a = {0.f, 0.f, 0.f, 0.f};
#pragma unroll
    for (int kk = 0; kk < 4; ++kk) {
      s16x8 bf = *(const s16x8*)(k + (long)(t * 16 + ll) * DQ_ + kk * 32 + lg * 8);
      a = mfma16(aq[kk], bf, a);
    }
#pragma unroll
    for (int i = 0; i < 4; ++i) {
      const int row = r0 + lg * 4 + i;
      const int col = t * 16 + ll;
      float s = a[i] * scale;
      if (mask0[row * L_ + col] != 0) s = 1e-9f;
      sc[t][i] = s;
    }
  }
#pragma unroll
  for (int i = 0; i < 4; ++i) {
    float mx = sc[0][i];
#pragma unroll
    for (int t = 1; t < 16; ++t) mx = fmaxf(mx, sc[t][i]);
#pragma unroll
    for (int d = 1; d < 16; d <<= 1) mx = fmaxf(mx, __shfl_xor(mx, d));
    float sum = 0.f;
#pragma unroll
    for (int t = 0; t < 16; ++t) {
      const float e = __expf(sc[t][i] - mx);
      sc[t][i] = e;
      sum += e;
    }
#pragma unroll
    for (int d = 1; d < 16; d <<= 1) sum += __shfl_xor(sum, d);
    const float inv = 1.f / sum;
    const int row = r0 + lg * 4 + i;
#pragma unroll
    for (int t = 0; t < 16; ++t)
      sc[t][i] = sc[t][i] * inv + biasb[(long)h * 65536 + (long)row * 256 + t * 16 + ll];
  }
  __shared__ float sm[16 * 256];
#pragma unroll
  for (int t = 0; t < 16; ++t)
#pragma unroll
    for (int i = 0; i < 4; ++i)
      sm[(lg * 4 + i) * 256 + t * 16 + ll] = sc[t][i];
  __syncthreads();
  s16x8 af[8];
#pragma unroll
  for (int kk = 0; kk < 8; ++kk) {
    const float* ap = &sm[ll * 256 + kk * 32 + lg * 8];
    s16x8 t8;
#pragma unroll
    for (int j = 0; j < 8; ++j) t8[j] = (short)f2bf(ap[j]);
    af[kk] = t8;
  }
#pragma unroll
  for (int n = 0; n < 8; ++n) {
    f32x4 a = {0.f, 0.f, 0.f, 0.f};
#pragma unroll
    for (int kk = 0; kk < 8; ++kk) {
      s16x8 bf = *(const s16x8*)(v + (long)(n * 16 + ll) * 256 + kk * 32 + lg * 8);
      a = mfma16(af[kk], bf, a);
    }
#pragma unroll
    for (int i = 0; i < 4; ++i) {
      const int row = r0 + lg * 4 + i;
      const int col = n * 16 + ll;
      hidden[(long)row * 1024 + h * 128 + col] = f2bf(a[i]);
    }
  }
}

// ---------------- layernorm over D=1024
// MODE 0: in f32 + add f32 (attn row, row%L), out bf16
// MODE 1: in bf16, out f32
template <int MODE>
__global__ __launch_bounds__(256) void ln_kernel(
    const void* __restrict__ in0v, const float* __restrict__ add1,
    const float* __restrict__ g, const float* __restrict__ bb,
    void* __restrict__ outv) {
  const int tid = threadIdx.x;
  const long row = blockIdx.x;
  float4 v;
  if constexpr (MODE == 0) {
    v = ((const float4*)((const float*)in0v + row * D_))[tid];
    const float4 u = ((const float4*)(add1 + (row & (L_ - 1)) * D_))[tid];
    v.x += u.x; v.y += u.y; v.z += u.z; v.w += u.w;
  } else {
    const uint2 pk = *(const uint2*)((const u16*)in0v + row * D_ + tid * 4);
    v.x = __uint_as_float((pk.x & 0xFFFFu) << 16);
    v.y = __uint_as_float(pk.x & 0xFFFF0000u);
    v.z = __uint_as_float((pk.y & 0xFFFFu) << 16);
    v.w = __uint_as_float(pk.y & 0xFFFF0000u);
  }
  float s = v.x + v.y + v.z + v.w;
  float q = v.x * v.x + v.y * v.y + v.z * v.z + v.w * v.w;
#pragma unroll
  for (int d = 1; d < 64; d <<= 1) { s += __shfl_xor(s, d); q += __shfl_xor(q, d); }
  __shared__ float ss[4], sq[4];
  const int wv = tid >> 6;
  if ((tid & 63) == 0) { ss[wv] = s; sq[wv] = q; }
  __syncthreads();
  s = ss[0] + ss[1] + ss[2] + ss[3];
  q = sq[0] + sq[1] + sq[2] + sq[3];
  const float mu = s * (1.f / D_);
  const float var = q * (1.f / D_) - mu * mu;
  const float rs = rsqrtf(var + 1e-5f);
  const float4 gv = ((const float4*)g)[tid];
  const float4 bv = ((const float4*)bb)[tid];
  float4 o;
  o.x = (v.x - mu) * rs * gv.x + bv.x;
  o.y = (v.y - mu) * rs * gv.y + bv.y;
  o.z = (v.z - mu) * rs * gv.z + bv.z;
  o.w = (v.w - mu) * rs * gv.w + bv.w;
  if constexpr (MODE == 0) {
    uint2 pk;
    pk.x = (unsigned)f2bf(o.x) | ((unsigned)f2bf(o.y) << 16);
    pk.y = (unsigned)f2bf(o.z) | ((unsigned)f2bf(o.w) << 16);
    *(uint2*)((u16*)outv + row * D_ + tid * 4) = pk;
  } else {
    ((float4*)((float*)outv + row * D_))[tid] = o;
  }
}

extern "C" void kernel_launch(void* const* d_in, const int* in_sizes, int n_in,
                              void* d_out, int out_size, void* d_ws, size_t ws_size,
                              hipStream_t stream) {
  (void)in_sizes; (void)n_in; (void)out_size; (void)ws_size;
  const float* src = (const float*)d_in[0];
  const float* sf = (const float*)d_in[1];
  const int* mask = (const int*)d_in[2];
  const float* qw = (const float*)d_in[3];
  const float* qb = (const float*)d_in[4];
  const float* kw = (const float*)d_in[5];
  const float* kb = (const float*)d_in[6];
  const float* vw = (const float*)d_in[7];
  const float* vb = (const float*)d_in[8];
  const float* b1w = (const float*)d_in[9];
  const float* b1b = (const float*)d_in[10];
  const float* b2w = (const float*)d_in[11];
  const float* b2b = (const float*)d_in[12];
  const float* ow = (const float*)d_in[13];
  const float* ob = (const float*)d_in[14];
  const float* ln1g = (const float*)d_in[15];
  const float* ln1b = (const float*)d_in[16];
  const float* ln2g = (const float*)d_in[17];
  const float* ln2b = (const float*)d_in[18];
  const float* w1 = (const float*)d_in[19];
  const float* bf1 = (const float*)d_in[20];
  const float* w2 = (const float*)d_in[21];
  const float* bf2 = (const float*)d_in[22];
  float* out = (float*)d_out;

  char* ws = (char*)d_ws;
  size_t off = 0;
  auto alloc = [&](size_t bytes) {
    void* p = ws + off;
    off += (bytes + 255) & ~(size_t)255;
    return p;
  };
  u16* qwT = (u16*)alloc((size_t)H_ * DQ_ * D_ * 2);
  u16* kwT = (u16*)alloc((size_t)H_ * DQ_ * D_ * 2);
  u16* vwT = (u16*)alloc((size_t)H_ * DQ_ * D_ * 2);
  u16* owT = (u16*)alloc((size_t)D_ * D_ * 2);
  u16* w1T = (u16*)alloc((size_t)DF_ * D_ * 2);
  u16* w2T = (u16*)alloc((size_t)D_ * DF_ * 2);
  u16* src0b = (u16*)alloc((size_t)L_ * D_ * 2);
  u16* q0 = (u16*)alloc((size_t)H_ * L_ * DQ_ * 2);
  u16* k0 = (u16*)alloc((size_t)H_ * L_ * DQ_ * 2);
  u16* v0T = (u16*)alloc((size_t)H_ * DQ_ * L_ * 2);
  float* nzv = (float*)alloc((size_t)H_ * DM_ * 4);
  int* nzi = (int*)alloc((size_t)H_ * DM_ * 4);
  int* nzcnt = (int*)alloc(256);
  float* biasb = (float*)alloc((size_t)H_ * L_ * L_ * 4);
  u16* hidden = (u16*)alloc((size_t)L_ * H_ * DQ_ * 2);
  float* attnvec = (float*)alloc((size_t)L_ * D_ * 4);
  u16* xb = (u16*)alloc((size_t)B_ * L_ * D_ * 2);
  u16* ffnh = (u16*)alloc((size_t)B_ * L_ * DF_ * 2);
  u16* yb = (u16*)alloc((size_t)B_ * L_ * D_ * 2);

  hipFuncSetAttribute((const void*)gemm8p<256, 1>,
                      hipFuncAttributeMaxDynamicSharedMemorySize, 131072);
  hipFuncSetAttribute((const void*)gemm8p<128, 2>,
                      hipFuncAttributeMaxDynamicSharedMemorySize, 98304);

  const dim3 b256(256);
  // phase 1: all weight transposes + src b0 conversion + hid (one launch)
  prep<<<dim3(12552), b256, 0, stream>>>(qw, kw, vw, ow, w1, w2, src, sf, b1w, b1b,
                                         qwT, kwT, vwT, owT, w1T, w2T, src0b, nzv,
                                         nzi, nzcnt);
  // phase 2: bias GEMV || QKV projections (one launch)
  phase2<<<dim3(560), b256, 0, stream>>>(nzv, nzi, nzcnt, b2w, b2b, biasb, src0b,
                                         qwT, kwT, vwT, qb, kb, vb, q0, k0, v0T);
  // attention (b=0) -> hidden [L][H*DQ] bf16
  attn_kernel<<<dim3(16, H_), dim3(64), 0, stream>>>(q0, k0, v0T, biasb, mask, hidden);
  // attn out projection -> attnvec [L][D] f32
  gemm_bt<<<dim3(2, 8), b256, 0, stream>>>(hidden, owT, attnvec, ob, D_, D_);
  // LN1: xb = bf16(LN(src + attn)) only
  ln_kernel<0><<<dim3(B_ * L_), b256, 0, stream>>>(src, attnvec, ln1g, ln1b, xb);
  // FFN1: relu(x @ w1 + bf1) -> ffnh bf16
  gemm8p<256, 1><<<dim3(512), dim3(512), 131072, stream>>>(
      xb, w1T, ffnh, bf1, nullptr, B_ * L_, DF_, D_, DF_);
  // FFN2: yb = bf16(ffnh @ w2 + bf2 + xb)
  gemm8p<128, 2><<<dim3(256), dim3(512), 98304, stream>>>(
      ffnh, w2T, yb, bf2, xb, B_ * L_, D_, DF_, D_);
  // LN2 -> d_out (f32)
  ln_kernel<1><<<dim3(B_ * L_), b256, 0, stream>>>(yb, nullptr, ln2g, ln2b, out);
}